// Round 2
// baseline (973.170 us; speedup 1.0000x reference)
//
#include <hip/hip_runtime.h>
#include <hip/hip_bf16.h>

typedef __bf16 bf16_t;
typedef bf16_t bf16x8 __attribute__((ext_vector_type(8)));
typedef float f32x4 __attribute__((ext_vector_type(4)));

// ---------------------------------------------------------------- helpers
__device__ __forceinline__ void gl_lds16(const bf16_t* g, bf16_t* l) {
  __builtin_amdgcn_global_load_lds(
      (const __attribute__((address_space(1))) void*)g,
      (__attribute__((address_space(3))) void*)l,
      16, 0, 0);
}

__device__ __forceinline__ void load8f(const bf16_t* p, float* f) {
  bf16x8 v = *(const bf16x8*)p;
#pragma unroll
  for (int e = 0; e < 8; ++e) f[e] = (float)v[e];
}
__device__ __forceinline__ void store8f(bf16_t* p, const float* f) {
  bf16x8 v;
#pragma unroll
  for (int e = 0; e < 8; ++e) v[e] = (bf16_t)f[e];
  *(bf16x8*)p = v;
}

// ---------------------------------------------------------------- fp32 -> bf16 (x)
__global__ __launch_bounds__(256) void cvt_f32_to_bf16(const float* __restrict__ in,
                                                       bf16_t* __restrict__ o) {
  size_t gid = (size_t)blockIdx.x * 256 + threadIdx.x;   // 4194304 threads, 8 elems each
  const float4* p = (const float4*)in + gid * 2;
  float4 a = p[0], b = p[1];
  bf16x8 v;
  v[0] = (bf16_t)a.x; v[1] = (bf16_t)a.y; v[2] = (bf16_t)a.z; v[3] = (bf16_t)a.w;
  v[4] = (bf16_t)b.x; v[5] = (bf16_t)b.y; v[6] = (bf16_t)b.z; v[7] = (bf16_t)b.w;
  *(bf16x8*)(o + gid * 8) = v;
}

// ---------------------------------------------------------------- weight transpose + cast: w[K][N] -> wT[N][K] bf16
__global__ __launch_bounds__(256) void transpose_to_bf16(const float* __restrict__ w,
                                                         bf16_t* __restrict__ wT,
                                                         int K, int N) {
  __shared__ float t[32][33];
  int bx = blockIdx.x;               // N tile
  int by = blockIdx.y;               // K tile
  int tx = threadIdx.x & 31, ty = threadIdx.x >> 5;   // 32 x 8
#pragma unroll
  for (int r = ty; r < 32; r += 8)
    t[r][tx] = w[(size_t)(by * 32 + r) * N + bx * 32 + tx];
  __syncthreads();
#pragma unroll
  for (int r = ty; r < 32; r += 8)
    wT[(size_t)(bx * 32 + r) * K + by * 32 + tx] = (bf16_t)t[tx][r];
}

// ---------------------------------------------------------------- GEMM: C[M][N] = A[M][K] @ Bt[N][K]^T
// 128x128 tile, BK=64, 4 waves, 16x16x32 bf16 MFMA, global_load_lds 16B (m97 structure)
// EPI 0: bf16 C, no bias.  EPI 1: fp32 C + bias.
template <int EPI>
__global__ __launch_bounds__(256) void gemm_bt(const bf16_t* __restrict__ A,
                                               const bf16_t* __restrict__ Bt,
                                               void* __restrict__ Cp,
                                               const float* __restrict__ bias,
                                               int M, int N, int K, int ldc) {
  __shared__ __align__(16) bf16_t As[128 * 64];
  __shared__ __align__(16) bf16_t Bs[128 * 64];
  const int tid = threadIdx.x;
  const int wave = tid >> 6, lane = tid & 63;
  const int bm0 = blockIdx.x * 128, bn0 = blockIdx.y * 128;
  const int wr = wave >> 1, wc = wave & 1;
  const int lr = lane & 15, lg = lane >> 4;

  f32x4 acc[4][4] = {};

  for (int kt = 0; kt < K; kt += 64) {
#pragma unroll
    for (int r = 0; r < 4; ++r) {
      int ci = (r * 4 + wave) * 64 + lane;     // 16B chunk index: 8 chunks per 64-elem row
      int mRow = ci >> 3, k8 = ci & 7;
      gl_lds16(A + (size_t)(bm0 + mRow) * K + kt + k8 * 8, &As[(r * 4 + wave) * 512]);
      gl_lds16(Bt + (size_t)(bn0 + mRow) * K + kt + k8 * 8, &Bs[(r * 4 + wave) * 512]);
    }
    __syncthreads();
#pragma unroll
    for (int kk = 0; kk < 64; kk += 32) {
      bf16x8 af[4], bfv[4];
#pragma unroll
      for (int i = 0; i < 4; ++i)
        af[i] = *(const bf16x8*)&As[(wr * 64 + i * 16 + lr) * 64 + kk + lg * 8];
#pragma unroll
      for (int j = 0; j < 4; ++j)
        bfv[j] = *(const bf16x8*)&Bs[(wc * 64 + j * 16 + lr) * 64 + kk + lg * 8];
#pragma unroll
      for (int i = 0; i < 4; ++i)
#pragma unroll
        for (int j = 0; j < 4; ++j)
          acc[i][j] = __builtin_amdgcn_mfma_f32_16x16x32_bf16(af[i], bfv[j], acc[i][j], 0, 0, 0);
    }
    __syncthreads();
  }

#pragma unroll
  for (int i = 0; i < 4; ++i)
#pragma unroll
    for (int j = 0; j < 4; ++j)
#pragma unroll
      for (int r = 0; r < 4; ++r) {
        int row = bm0 + wr * 64 + i * 16 + lg * 4 + r;
        int col = bn0 + wc * 64 + j * 16 + lr;
        float v = acc[i][j][r];
        if (EPI == 0) {
          ((bf16_t*)Cp)[(size_t)row * ldc + col] = (bf16_t)v;
        } else {
          ((float*)Cp)[(size_t)row * ldc + col] = v + bias[col];
        }
      }
}

// ---------------------------------------------------------------- pyramid coarsen: level-1 from C1, else from pyramid
// q,k: pairwise mean; v: pairwise sum.  Pyramid layout: P[hg][8160 rows][64] bf16.
__global__ __launch_bounds__(256) void coarsen(const bf16_t* __restrict__ C1,
                                               bf16_t* __restrict__ Pq,
                                               bf16_t* __restrict__ Pk,
                                               bf16_t* __restrict__ Pv,
                                               int level, int mshift, int poffIn, int poffOut) {
  int gid = blockIdx.x * 256 + threadIdx.x;
  int d8 = gid & 7;
  int r = (gid >> 3) & ((1 << mshift) - 1);
  int hg = gid >> (3 + mshift);
  if (hg >= 64) return;

  const bf16_t *sq0, *sq1, *sk0, *sk1, *sv0, *sv1;
  if (level == 1) {
    size_t base0 = ((size_t)(hg >> 4) * 8192 + 2 * r) * 3072 + (hg & 15) * 64 + d8 * 8;
    size_t base1 = base0 + 3072;
    sq0 = C1 + base0;        sq1 = C1 + base1;
    sk0 = C1 + base0 + 1024; sk1 = C1 + base1 + 1024;
    sv0 = C1 + base0 + 2048; sv1 = C1 + base1 + 2048;
  } else {
    size_t b0 = ((size_t)hg * 8160 + poffIn + 2 * r) * 64 + d8 * 8;
    size_t b1 = b0 + 64;
    sq0 = Pq + b0; sq1 = Pq + b1;
    sk0 = Pk + b0; sk1 = Pk + b1;
    sv0 = Pv + b0; sv1 = Pv + b1;
  }
  float q0[8], q1[8], k0[8], k1[8], v0[8], v1[8], qo[8], ko[8], vo[8];
  load8f(sq0, q0); load8f(sq1, q1);
  load8f(sk0, k0); load8f(sk1, k1);
  load8f(sv0, v0); load8f(sv1, v1);
#pragma unroll
  for (int e = 0; e < 8; ++e) {
    qo[e] = 0.5f * (q0[e] + q1[e]);
    ko[e] = 0.5f * (k0[e] + k1[e]);
    vo[e] = v0[e] + v1[e];
  }
  size_t o = ((size_t)hg * 8160 + poffOut + r) * 64 + d8 * 8;
  store8f(Pq + o, qo);
  store8f(Pk + o, ko);
  store8f(Pv + o, vo);
}

// ---------------------------------------------------------------- per-level 16x16 block attention
// One workgroup (256 thr) per (hg, block). Partner kv block = blk^1 on coarse levels (flip), blk on finest.
// IS_L0=1: finest level -> reads C1, writes fp32 Y0 (lives in d_out). IS_L0=0: coarse -> reads P, writes bf16 Yc.
template <int IS_L0>
__global__ __launch_bounds__(256) void attn_kernel(const bf16_t* __restrict__ C1,
                                                   const bf16_t* __restrict__ Pq,
                                                   const bf16_t* __restrict__ Pk,
                                                   const bf16_t* __restrict__ Pv,
                                                   float* __restrict__ Y0,
                                                   bf16_t* __restrict__ Yc,
                                                   float* __restrict__ Asum,
                                                   int lg2nblk, int poff, int aoff) {
  __shared__ float qs[16 * 64];
  __shared__ float ks[16 * 65];
  __shared__ float vs[16 * 64];
  __shared__ float SA[16 * 17];
  const int tid = threadIdx.x;
  const int blk = blockIdx.x & ((1 << lg2nblk) - 1);
  const int hg = blockIdx.x >> lg2nblk;
  const int kvblk = IS_L0 ? blk : (blk ^ 1);

  for (int c = tid; c < 384; c += 256) {
    int tns = c >> 7;                // 0=q 1=k 2=v
    int idx = c & 127;
    int i = idx >> 3, d8 = idx & 7;
    int srcBlk = (tns == 0) ? blk : kvblk;
    int t = srcBlk * 16 + i;
    const bf16_t* src;
    if (IS_L0) {
      src = C1 + ((size_t)(hg >> 4) * 8192 + t) * 3072 + (hg & 15) * 64 + tns * 1024 + d8 * 8;
    } else {
      const bf16_t* P = (tns == 0) ? Pq : (tns == 1 ? Pk : Pv);
      src = P + ((size_t)hg * 8160 + poff + t) * 64 + d8 * 8;
    }
    bf16x8 v = *(const bf16x8*)src;
    float* dst = (tns == 0) ? &qs[i * 64 + d8 * 8]
                            : (tns == 1 ? &ks[i * 65 + d8 * 8] : &vs[i * 64 + d8 * 8]);
#pragma unroll
    for (int e = 0; e < 8; ++e) dst[e] = (float)v[e];
  }
  __syncthreads();

  const int i = tid >> 4, j = tid & 15;
  float s = 0.f;
#pragma unroll
  for (int d = 0; d < 64; ++d) s += qs[i * 64 + d] * ks[j * 65 + d];
  s *= 0.125f;                       // DIM_HEAD^-0.5
  float mx = s;
#pragma unroll
  for (int m = 8; m >= 1; m >>= 1) mx = fmaxf(mx, __shfl_xor(mx, m, 64));
  float a = expf(s - mx);
  float as = a;
#pragma unroll
  for (int m = 8; m >= 1; m >>= 1) as += __shfl_xor(as, m, 64);
  SA[i * 17 + j] = a;
  if (j == 0) Asum[(size_t)hg * 16352 + aoff + blk * 16 + i] = as;
  __syncthreads();

#pragma unroll
  for (int e = 0; e < 4; ++e) {
    int idx = tid + e * 256;
    int ii = idx >> 6, d = idx & 63;
    float y = 0.f;
#pragma unroll
    for (int jj = 0; jj < 16; ++jj) y += SA[ii * 17 + jj] * vs[jj * 64 + d];
    if (IS_L0) {
      Y0[((size_t)hg * 8192 + blk * 16 + ii) * 64 + d] = y;
    } else {
      Yc[((size_t)hg * 8160 + poff + blk * 16 + ii) * 64 + d] = (bf16_t)y;
    }
  }
}

// ---------------------------------------------------------------- combine levels + normalize -> attn bf16 [32768][1024]
__global__ __launch_bounds__(256) void combine_kernel(const float* __restrict__ Y0,
                                                      const bf16_t* __restrict__ Yc,
                                                      const float* __restrict__ As,
                                                      bf16_t* __restrict__ attnb) {
  int gid = blockIdx.x * 256 + threadIdx.x;
  int d8 = gid & 7;
  int t = (gid >> 3) & 8191;
  int hg = gid >> 16;
  const int poffA[9] = {0, 0, 4096, 6144, 7168, 7680, 7936, 8064, 8128};
  const int aoffA[9] = {0, 8192, 12288, 14336, 15360, 15872, 16128, 16256, 16320};
  float acc[8];
  float asum = As[(size_t)hg * 16352 + t];
  {
    const float4* yp = (const float4*)(Y0 + ((size_t)hg * 8192 + t) * 64 + d8 * 8);
    float4 y0 = yp[0], y1 = yp[1];
    acc[0] = y0.x; acc[1] = y0.y; acc[2] = y0.z; acc[3] = y0.w;
    acc[4] = y1.x; acc[5] = y1.y; acc[6] = y1.z; acc[7] = y1.w;
  }
#pragma unroll
  for (int l = 1; l < 9; ++l) {
    int rc = t >> l;
    asum += As[(size_t)hg * 16352 + aoffA[l] + rc];
    bf16x8 v = *(const bf16x8*)(Yc + ((size_t)hg * 8160 + poffA[l] + rc) * 64 + d8 * 8);
#pragma unroll
    for (int e = 0; e < 8; ++e) acc[e] += (float)v[e];
  }
  float inv = 1.f / (asum + 1e-8f);
  bf16x8 v;
#pragma unroll
  for (int e = 0; e < 8; ++e) v[e] = (bf16_t)(acc[e] * inv);
  *(bf16x8*)(attnb + ((size_t)(hg >> 4) * 8192 + t) * 1024 + (hg & 15) * 64 + d8 * 8) = v;
}

// ---------------------------------------------------------------- launch
// Workspace plan (bytes), total 474,996,736 (~453 MiB):
//   C1    @ 0           192 MiB  [32768][3072] bf16 qkv      (live: gemm1 .. attn L0)
//   Pq    @ 201326592   63.75MiB [64][8160][64] bf16          (live: coarsen .. attn coarse)
//   Pk    @ 268173312   63.75MiB
//   Pv    @ 335020032   63.75MiB
//   Yc    @ 401866752   63.75MiB [64][8160][64] bf16 coarse Y (live: attn coarse .. combine)
//   Ab    @ 468713472   4 MiB    [64][16352] f32 Asum
//   woutT @ 472899584   2 MiB    [1024][1024] bf16            (live: transpose .. gemm2)
// Aliases (liveness-checked, stream-ordered):
//   x_bf  @ 401866752 (over Yc+Ab head; dead after gemm1, Yc/Ab written later)
//   wqkvT @ 201326592 (over Pq; dead after gemm1, Pq written later)
//   attnb @ 268173312 (over Pk; written by combine after pyramid is dead)
//   Y0 (fine fp32 [64][8192][64] = 128 MiB) lives in d_out; fully overwritten by gemm2 at the end.
extern "C" void kernel_launch(void* const* d_in, const int* in_sizes, int n_in,
                              void* d_out, int out_size, void* d_ws, size_t ws_size,
                              hipStream_t stream) {
  const float* x = (const float*)d_in[0];     // [4][8192][1024]
  const float* wqkv = (const float*)d_in[1];  // [1024][3072]
  const float* wout = (const float*)d_in[2];  // [1024][1024]
  const float* bout = (const float*)d_in[3];  // [1024]
  float* out = (float*)d_out;                 // [32768][1024] fp32
  (void)in_sizes; (void)n_in; (void)out_size; (void)ws_size;

  char* base = (char*)d_ws;
  bf16_t* C1    = (bf16_t*)(base + 0);
  bf16_t* Pq    = (bf16_t*)(base + 201326592);
  bf16_t* Pk    = (bf16_t*)(base + 268173312);
  bf16_t* Pv    = (bf16_t*)(base + 335020032);
  bf16_t* Yc    = (bf16_t*)(base + 401866752);
  float*  Ab    = (float*)(base + 468713472);
  bf16_t* woutT = (bf16_t*)(base + 472899584);
  bf16_t* x_bf  = (bf16_t*)(base + 401866752);   // alias over Yc/Ab
  bf16_t* wqkvT = (bf16_t*)(base + 201326592);   // alias over Pq
  bf16_t* attnb = (bf16_t*)(base + 268173312);   // alias over Pk
  float*  Y0    = out;                           // fine-level Y lives in d_out

  cvt_f32_to_bf16<<<16384, 256, 0, stream>>>(x, x_bf);
  transpose_to_bf16<<<dim3(3072 / 32, 1024 / 32), 256, 0, stream>>>(wqkv, wqkvT, 1024, 3072);
  transpose_to_bf16<<<dim3(1024 / 32, 1024 / 32), 256, 0, stream>>>(wout, woutT, 1024, 1024);

  gemm_bt<0><<<dim3(256, 24), 256, 0, stream>>>(x_bf, wqkvT, (void*)C1, nullptr,
                                                32768, 3072, 1024, 3072);

  static const int poffA[9] = {0, 0, 4096, 6144, 7168, 7680, 7936, 8064, 8128};
  static const int aoffA[9] = {0, 8192, 12288, 14336, 15360, 15872, 16128, 16256, 16320};

  for (int l = 1; l <= 8; ++l) {
    int mshift = 13 - l;                 // log2 of output rows per head-group
    coarsen<<<2 << mshift, 256, 0, stream>>>(C1, Pq, Pk, Pv, l, mshift, poffA[l - 1], poffA[l]);
  }
  attn_kernel<1><<<64 << 9, 256, 0, stream>>>(C1, Pq, Pk, Pv, Y0, Yc, Ab, 9, 0, 0);
  for (int l = 1; l <= 8; ++l) {
    attn_kernel<0><<<64 << (9 - l), 256, 0, stream>>>(C1, Pq, Pk, Pv, Y0, Yc, Ab,
                                                      9 - l, poffA[l], aoffA[l]);
  }
  combine_kernel<<<16384, 256, 0, stream>>>(Y0, Yc, Ab, attnb);

  gemm_bt<1><<<dim3(256, 8), 256, 0, stream>>>(attnb, woutT, (void*)out, bout,
                                               32768, 1024, 1024, 1024);
}